// Round 15
// baseline (1102.779 us; speedup 1.0000x reference)
//
#include <hip/hip_runtime.h>
#include <math.h>

constexpr int BB = 4;       // batch
constexpr int SS = 1000;    // seq len
constexpr int INDIM = 5;
constexpr int EE = 256;     // embed
constexpr int LL = 6;       // layers
constexpr int HH = 8;       // heads
constexpr int DHH = 32;     // head dim
constexpr int NLM = 50;     // landmarks
constexpr int FFD = 1024;   // ff hidden
constexpr int NCONV = 576;  // weight-conversion blocks fused into phembed

constexpr long long WSEG = (long long)LL * EE * EE;        // qw/kw/vw/ow each
constexpr long long WFF  = (long long)LL * FFD * EE;       // fw1/fw2 each
constexpr long long WTOT = 4 * WSEG + 2 * WFF;

typedef short short8 __attribute__((ext_vector_type(8)));
typedef float f32x4 __attribute__((ext_vector_type(4)));
typedef unsigned short u16;
typedef unsigned long long u64;

__device__ inline u16 f2b(float f) {
  union { float f; unsigned u; } v; v.f = f;
  unsigned u = v.u;
  unsigned r = u + 0x7FFFu + ((u >> 16) & 1u);  // round-to-nearest-even
  return (u16)(r >> 16);
}
__device__ inline float b2f(u16 b) {
  union { unsigned u; float f; } v; v.u = ((unsigned)b) << 16;
  return v.f;
}
__device__ inline short8 pack8(float4 a, float4 b) {
  short8 r;
  r[0] = (short)f2b(a.x); r[1] = (short)f2b(a.y);
  r[2] = (short)f2b(a.z); r[3] = (short)f2b(a.w);
  r[4] = (short)f2b(b.x); r[5] = (short)f2b(b.y);
  r[6] = (short)f2b(b.z); r[7] = (short)f2b(b.w);
  return r;
}

__device__ inline double wred_sum(double v) {
#pragma unroll
  for (int m = 1; m < 64; m <<= 1) v += __shfl_xor(v, m, 64);
  return v;
}
__device__ inline double wred_min(double v) {
#pragma unroll
  for (int m = 1; m < 64; m <<= 1) v = fmin(v, __shfl_xor(v, m, 64));
  return v;
}
__device__ inline double wred_max(double v) {
#pragma unroll
  for (int m = 1; m < 64; m <<= 1) v = fmax(v, __shfl_xor(v, m, 64));
  return v;
}
__device__ inline float wredf_sum(float v) {
#pragma unroll
  for (int m = 1; m < 64; m <<= 1) v += __shfl_xor(v, m, 64);
  return v;
}
__device__ inline int sgnbit(double x) {
  return (int)((unsigned long long)__double_as_longlong(x) >> 63);
}

// ---------------------------------------------------------------------------
// Fused 256-thread kernel:
//   blocks [0,4)            : ph (4-wave LDS Householder, trailing-range split)
//   blocks [4,1004)         : embed (4 rows/block, one per wave)
//   blocks [1004,1004+NCONV): weight f32->bf16 conversion (overlaps ph)
// ---------------------------------------------------------------------------
struct PhS {
  double matA[NLM][51];
  union {
    u64 keys[1024];
    double vstore[NLM - 2][64];
  } u;
  double vbuf[64], wbuf[64];
  double pm[4][64];
  double dar[NLM], ear[NLM], e2a[NLM], tauA[NLM], evs[NLM];
  double gdl[NLM], gdd[NLM], gdu[NLM], gdu2[NLM], gz[NLM];
  float sm[SS];
  float lx[NLM], ly[NLM];
};
union FusedS { PhS ph; float h[4][128]; };

__global__ __launch_bounds__(256) void phembed_kernel(
    const float* __restrict__ seq, const float* __restrict__ ph_fw,
    const float* __restrict__ ph_db, const float* __restrict__ ph_law,
    const float* __restrict__ ph_lab, float* __restrict__ pf,
    const float* __restrict__ ew1, const float* __restrict__ eb1,
    const float* __restrict__ ew2, const float* __restrict__ eb2,
    const float* __restrict__ eg, const float* __restrict__ ebe,
    const float* __restrict__ pos, float* __restrict__ X, u16* __restrict__ Xb,
    const float* __restrict__ qw, const float* __restrict__ kw,
    const float* __restrict__ vw, const float* __restrict__ ow,
    const float* __restrict__ fw1, const float* __restrict__ fw2,
    u16* __restrict__ Wb)
{
  __shared__ FusedS S;
  const int tid = threadIdx.x;
  const int lane = tid & 63, wid = tid >> 6;

  if (blockIdx.x >= BB + SS) {
    // ===================== weight conversion path =====================
    const int cb = blockIdx.x - (BB + SS);
#pragma unroll
    for (int it = 0; it < 4; ++it) {
      long long v = ((long long)cb * 4 + it) * 256 + tid;
      long long e = v * 8;
      if (e >= WTOT) break;
      const float* src; long long off;
      if (e < WSEG)          { src = qw;  off = e; }
      else if (e < 2 * WSEG) { src = kw;  off = e - WSEG; }
      else if (e < 3 * WSEG) { src = vw;  off = e - 2 * WSEG; }
      else if (e < 4 * WSEG) { src = ow;  off = e - 3 * WSEG; }
      else if (e < 4 * WSEG + WFF) { src = fw1; off = e - 4 * WSEG; }
      else                   { src = fw2; off = e - 4 * WSEG - WFF; }
      float4 a = *(const float4*)(src + off);
      float4 b = *(const float4*)(src + off + 4);
      *(short8*)(Wb + e) = pack8(a, b);
    }
    return;
  }

  if (blockIdx.x < BB) {
    // ===================== ph path =====================
    const int b = blockIdx.x;
    PhS& P = S.ph;
    const float law0 = ph_law[0], law1 = ph_law[1], labv = ph_lab[0];
    for (int s = tid; s < 1024; s += 256) {
      u64 key;
      if (s < SS) {
        const float* p = seq + ((size_t)b * SS + s) * INDIM;
        float m = (p[0] + p[1] + p[2] + p[3] + p[4]) * 0.2f;
        P.sm[s] = m;
        float sc = (float)s * law0 + m * law1 + labv;
        unsigned u = __float_as_uint(sc);
        unsigned asc = (u & 0x80000000u) ? ~u : (u | 0x80000000u);
        key = ((u64)(~asc) << 32) | (unsigned)s;
      } else {
        key = (0xFFFFFFFFull << 32) | (unsigned)s;
      }
      P.u.keys[s] = key;
    }
    __syncthreads();
    for (int k = 2; k <= 1024; k <<= 1) {
      for (int j = k >> 1; j > 0; j >>= 1) {
        for (int i = tid; i < 1024; i += 256) {
          int ixj = i ^ j;
          if (ixj > i) {
            u64 a = P.u.keys[i], c = P.u.keys[ixj];
            bool up = ((i & k) == 0);
            if ((a > c) == up) { P.u.keys[i] = c; P.u.keys[ixj] = a; }
          }
        }
        __syncthreads();
      }
    }
    if (tid < NLM) {
      int id = (int)(P.u.keys[tid] & 0xFFFFFFFFull);
      P.lx[tid] = (float)id;
      P.ly[tid] = P.sm[id];
    }
    __syncthreads();   // keys dead; vstore aliases
    const float fwv = fabsf(ph_fw[0]);
    const float dbv = ph_db[0];
    for (int t = tid; t < NLM * NLM; t += 256) {
      int i = t / NLM, j = t % NLM;
      float dx = P.lx[i] - P.lx[j], dy = P.ly[i] - P.ly[j];
      float d2 = dx * dx + dy * dy;
      float dist = (d2 > 0.f) ? sqrtf(d2) : 0.f;
      float Kv = expf(-(dist * fwv + dbv));
      P.matA[i][j] = -(double)Kv;
    }
    __syncthreads();
    if (tid < NLM) {
      double rsum = 0.0;
      for (int j = 0; j < NLM; ++j) rsum -= P.matA[tid][j];
      P.matA[tid][tid] += rsum;  // exact cancellation -> lambda0 ~ 1e-15
    }
    __syncthreads();

    for (int k = 0; k <= NLM - 3; ++k) {
      const int m = NLM - 1 - k;
      if (wid == 0) {
        double x = (lane > k && lane < NLM) ? P.matA[lane][k] : 0.0;
        double x0 = __shfl(x, k + 1, 64);
        double sigma = wred_sum((lane > k + 1) ? x * x : 0.0);
        double beta, tau, scale;
        if (sigma == 0.0) { beta = x0; tau = 0.0; scale = 0.0; }
        else {
          double nrm = sqrt(x0 * x0 + sigma);
          beta = (x0 >= 0.0) ? -nrm : nrm;
          tau = (beta - x0) / beta;
          scale = 1.0 / (x0 - beta);
        }
        double v = (lane == k + 1) ? 1.0 : ((lane > k + 1 && lane < NLM) ? x * scale : 0.0);
        P.vbuf[lane] = v;
        P.u.vstore[k][lane] = v;
        if (lane == 0) { P.ear[k] = beta; P.tauA[k] = tau; }
      }
      __syncthreads();
      {
        int chunk = (m + 3) >> 2;
        int j0 = k + 1 + wid * chunk;
        int j1 = j0 + chunk; if (j1 > NLM) j1 = NLM;
        double partial = 0.0;
        if (lane < NLM)
          for (int j = j0; j < j1; ++j) partial += P.matA[lane][j] * P.vbuf[j];
        P.pm[wid][lane] = partial;
      }
      __syncthreads();
      if (wid == 0) {
        double tau = P.tauA[k];
        double p = 0.0;
        if (lane < NLM)
          p = (P.pm[0][lane] + P.pm[1][lane] + P.pm[2][lane] + P.pm[3][lane]) * tau;
        double vr = P.vbuf[lane];
        double dotvp = wred_sum(vr * p);
        double w = p - 0.5 * tau * dotvp * vr;
        P.wbuf[lane] = (lane < NLM) ? w : 0.0;
      }
      __syncthreads();
      {
        int chunk = (m + 4) >> 2;
        int j0 = k + wid * chunk;
        int j1 = j0 + chunk; if (j1 > NLM) j1 = NLM;
        if (lane < NLM) {
          double vr = P.vbuf[lane], wr = P.wbuf[lane];
          for (int j = j0; j < j1; ++j)
            P.matA[lane][j] -= vr * P.wbuf[j] + wr * P.vbuf[j];
        }
      }
      __syncthreads();
    }
    if (tid < NLM) P.dar[tid] = P.matA[tid][tid];
    if (tid == 0) P.ear[NLM - 2] = P.matA[NLM - 1][NLM - 2];
    __syncthreads();
    if (tid < NLM - 1) P.e2a[tid] = P.ear[tid] * P.ear[tid];
    __syncthreads();

    double lo_i = 1e300, hi_i = -1e300;
    if (lane < NLM) {
      double rl = (lane > 0) ? fabs(P.ear[lane - 1]) : 0.0;
      double rr = (lane < NLM - 1) ? fabs(P.ear[lane]) : 0.0;
      double dd = P.dar[lane];
      lo_i = dd - rl - rr;
      hi_i = dd + rl + rr;
    }
    double glo = wred_min(lo_i), ghi = wred_max(hi_i);

    if (tid < 100) {
      const int e = tid >> 1;
      const int side = tid & 1;
      const int need = e + 1;
      double lo = glo, hi = ghi;
      for (int it = 0; it < 24; ++it) {
        double third = (hi - lo) * (1.0 / 3.0);
        double x1 = lo + third, x2 = hi - third;
        double x = side ? x2 : x1;
        double p = P.dar[0] - x, q = 1.0;
        int c = sgnbit(p);
#pragma unroll 7
        for (int i = 1; i < NLM; ++i) {
          double n = (P.dar[i] - x) * p - P.e2a[i - 1] * q;
          if (n == 0.0) n = sgnbit(p) ? -1e-300 : 1e-300;
          c += (sgnbit(n) != sgnbit(p));
          long long an = __double_as_longlong(n) & 0x7fffffffffffffffLL;
          long long ap = __double_as_longlong(p) & 0x7fffffffffffffffLL;
          int E = (int)((an > ap ? an : ap) >> 52);
          int se = 2046 - E; se = se < 1 ? 1 : (se > 2045 ? 2045 : se);
          double s = __longlong_as_double((long long)se << 52);
          q = p * s; p = n * s;
        }
        int cp = __shfl_xor(c, 1, 64);
        int c1 = side ? cp : c;
        int c2 = side ? c : cp;
        if (c1 >= need) hi = x1;
        else if (c2 >= need) { lo = x1; hi = x2; }
        else lo = x2;
      }
      if (side == 0) P.evs[e] = 0.5 * (lo + hi);
    }
    __syncthreads();

    if (wid != 0) return;

    if (lane == 0) {
      double shift = P.evs[1];
      unsigned rs = 12345u;
      for (int i = 0; i < NLM; ++i) {
        rs = rs * 1103515245u + 12345u;
        P.gz[i] = ((double)((rs >> 8) & 0xFFFF)) / 65536.0 - 0.5;
      }
      for (int iter = 0; iter < 2; ++iter) {
        for (int i = 0; i < NLM; ++i) P.gdd[i] = P.dar[i] - shift;
        for (int i = 0; i < NLM - 1; ++i) { P.gdl[i] = P.ear[i]; P.gdu[i] = P.ear[i]; }
        for (int i = 0; i < NLM - 1; ++i) {
          if (fabs(P.gdd[i]) >= fabs(P.gdl[i])) {
            if (P.gdd[i] == 0.0) P.gdd[i] = 1e-280;
            double fact = P.gdl[i] / P.gdd[i];
            P.gdd[i + 1] -= fact * P.gdu[i];
            P.gz[i + 1] -= fact * P.gz[i];
            if (i < NLM - 2) P.gdu2[i] = 0.0;
          } else {
            double fact = P.gdd[i] / P.gdl[i];
            P.gdd[i] = P.gdl[i];
            double tmp = P.gdd[i + 1];
            P.gdd[i + 1] = P.gdu[i] - fact * tmp;
            if (i < NLM - 2) { P.gdu2[i] = P.gdu[i + 1]; P.gdu[i + 1] = -fact * P.gdu2[i]; }
            P.gdu[i] = tmp;
            double tz = P.gz[i]; P.gz[i] = P.gz[i + 1]; P.gz[i + 1] = tz - fact * P.gz[i];
          }
        }
        if (P.gdd[NLM - 1] == 0.0) P.gdd[NLM - 1] = 1e-280;
        P.gz[NLM - 1] /= P.gdd[NLM - 1];
        P.gz[NLM - 2] = (P.gz[NLM - 2] - P.gdu[NLM - 2] * P.gz[NLM - 1]) / P.gdd[NLM - 2];
        for (int i = NLM - 3; i >= 0; --i)
          P.gz[i] = (P.gz[i] - P.gdu[i] * P.gz[i + 1] - P.gdu2[i] * P.gz[i + 2]) / P.gdd[i];
        double nr = 0.0;
        for (int i = 0; i < NLM; ++i) nr += P.gz[i] * P.gz[i];
        nr = sqrt(nr);
        for (int i = 0; i < NLM; ++i) P.gz[i] /= nr;
      }
    }
    __builtin_amdgcn_wave_barrier();
    double fied = (lane < NLM) ? P.gz[lane] : 0.0;
    for (int k = NLM - 3; k >= 0; --k) {
      double v = P.u.vstore[k][lane];
      double dot = wred_sum(v * fied);
      fied -= P.tauA[k] * dot * v;
    }

    double myev = (lane < NLM) ? P.evs[lane] : 1e300;
    bool inR = (lane < NLM);
    double n0 = wred_sum((inR && myev < 1e-6) ? 1.0 : 0.0);
    double s0 = wred_sum((inR && myev < 1e-6) ? fabs(myev) : 0.0);
    double e0 = P.evs[0], e1 = P.evs[1];
    double e2 = P.evs[2], e3 = P.evs[3], e4 = P.evs[4], e5 = P.evs[5];
    double gap = e1 - e0;
    double m4 = (e2 + e3 + e4 + e5) * 0.25;
    double v4 = ((e2 - m4) * (e2 - m4) + (e3 - m4) * (e3 - m4) +
                 (e4 - m4) * (e4 - m4) + (e5 - m4) * (e5 - m4)) / 3.0;
    double fmean = wred_sum(inR ? fied : 0.0) / NLM;
    double fd = inR ? (fied - fmean) : 0.0;
    double fvar = wred_sum(fd * fd) / (NLM - 1);
    if (lane == 0) {
      float* o = pf + b * 6;
      o[0] = (float)n0;
      o[1] = (float)s0;
      o[2] = (float)gap;
      o[3] = (float)sqrt(fvar);
      o[4] = (float)m4;
      o[5] = (float)sqrt(v4);
    }
    return;
  }

  // ===================== embed path: 4 rows/block, one per wave =====================
  const int row = (blockIdx.x - BB) * 4 + wid;
  const int s = row % SS;
  float* hb = S.h[wid];
  float sv0, sv1, sv2, sv3, sv4;
  {
    const float* p = seq + (size_t)row * INDIM;
    sv0 = p[0]; sv1 = p[1]; sv2 = p[2]; sv3 = p[3]; sv4 = p[4];
  }
#pragma unroll
  for (int half = 0; half < 2; ++half) {
    int j = lane + half * 64;
    const float* w = ew1 + j * INDIM;
    float a = eb1[j] + w[0] * sv0 + w[1] * sv1 + w[2] * sv2 + w[3] * sv3 + w[4] * sv4;
    hb[j] = fmaxf(a, 0.f);
  }
  __builtin_amdgcn_wave_barrier();
  float o4[4];
#pragma unroll
  for (int q = 0; q < 4; ++q) {
    int e = lane * 4 + q;
    const float* w = ew2 + (size_t)e * 128;
    float a0 = 0.f, a1 = 0.f;
    for (int i = 0; i < 128; i += 8) {
      float4 wa = *(const float4*)(w + i);
      float4 wb = *(const float4*)(w + i + 4);
      a0 += wa.x * hb[i] + wa.y * hb[i + 1] + wa.z * hb[i + 2] + wa.w * hb[i + 3];
      a1 += wb.x * hb[i + 4] + wb.y * hb[i + 5] + wb.z * hb[i + 6] + wb.w * hb[i + 7];
    }
    o4[q] = eb2[e] + a0 + a1;
  }
  float ssum = o4[0] + o4[1] + o4[2] + o4[3];
  ssum = wredf_sum(ssum);
  float mean = ssum * (1.f / EE);
  float d0 = o4[0] - mean, d1 = o4[1] - mean, d2 = o4[2] - mean, d3 = o4[3] - mean;
  float qsum = d0 * d0 + d1 * d1 + d2 * d2 + d3 * d3;
  qsum = wredf_sum(qsum);
  float inv = rsqrtf(qsum * (1.f / EE) + 1e-5f);
  float4 gv = *(const float4*)(eg + lane * 4);
  float4 bv = *(const float4*)(ebe + lane * 4);
  float4 pv = *(const float4*)(pos + (size_t)s * EE + lane * 4);
  float4 outv = make_float4(d0 * inv * gv.x + bv.x + pv.x,
                            d1 * inv * gv.y + bv.y + pv.y,
                            d2 * inv * gv.z + bv.z + pv.z,
                            d3 * inv * gv.w + bv.w + pv.w);
  *(float4*)(X + (size_t)row * EE + lane * 4) = outv;
  *(ushort4*)(Xb + (size_t)row * EE + lane * 4) =
      make_ushort4(f2b(outv.x), f2b(outv.y), f2b(outv.z), f2b(outv.w));
}

// ---------------------------------------------------------------------------
// Per-(layer,batch) scalar attention temperature
// ---------------------------------------------------------------------------
__global__ __launch_bounds__(256) void temp_kernel(
    const float* __restrict__ pf, const float* __restrict__ w1, const float* __restrict__ b1,
    const float* __restrict__ w2, const float* __restrict__ b2, float* __restrict__ ts)
{
  const int l = blockIdx.x / BB, b = blockIdx.x % BB, tid = threadIdx.x;
  __shared__ float pfl[6];
  __shared__ float h[128];
  __shared__ float red[256];
  if (tid < 6) pfl[tid] = pf[b * 6 + tid];
  __syncthreads();
  if (tid < 128) {
    const float* w = w1 + ((size_t)l * 128 + tid) * 6;
    float a = b1[(size_t)l * 128 + tid];
#pragma unroll
    for (int i = 0; i < 6; ++i) a += w[i] * pfl[i];
    h[tid] = fmaxf(a, 0.f);
  }
  __syncthreads();
  const float* w = w2 + ((size_t)l * EE + tid) * 128;
  float a = b2[(size_t)l * EE + tid];
  for (int i = 0; i < 128; ++i) a += w[i] * h[i];
  float sg = 1.f / (1.f + expf(-a));
  red[tid] = sg; __syncthreads();
  for (int wd = 128; wd > 0; wd >>= 1) { if (tid < wd) red[tid] += red[tid + wd]; __syncthreads(); }
  if (tid == 0) ts[l * BB + b] = red[0] * (1.f / EE);
}

// ---------------------------------------------------------------------------
// bf16 MFMA GEMM: C(bf16) = A[MxK] @ W[NxK]^T + bias. W pre-converted bf16.
// ---------------------------------------------------------------------------
template <int ACT>
__global__ __launch_bounds__(256) void gemm_bt(
    const u16* __restrict__ Ab,
    const u16* __restrict__ W0, const u16* __restrict__ W1, const u16* __restrict__ W2,
    const float* __restrict__ bb0, const float* __restrict__ bb1, const float* __restrict__ bb2,
    u16* __restrict__ C0, u16* __restrict__ C1, u16* __restrict__ C2,
    int M, int N, int K)
{
  const int z = blockIdx.z;
  const u16* W = (z == 0) ? W0 : (z == 1) ? W1 : W2;
  const float* bias = (z == 0) ? bb0 : (z == 1) ? bb1 : bb2;
  u16* C = (z == 0) ? C0 : (z == 1) ? C1 : C2;
  __shared__ __align__(16) u16 As[2][64][40];
  __shared__ __align__(16) u16 Bs[2][64][40];
  const int m0 = blockIdx.x * 64, n0 = blockIdx.y * 64;
  const int tid = threadIdx.x;
  const int lane = tid & 63, wave = tid >> 6;
  const int wm = wave >> 1, wn = wave & 1;
  const int l15 = lane & 15, l4 = lane >> 4;
  const int srow = tid >> 2, scg = (tid & 3) * 8;

  f32x4 acc[2][2];
#pragma unroll
  for (int i = 0; i < 2; ++i)
#pragma unroll
    for (int j = 0; j < 2; ++j) acc[i][j] = (f32x4){0.f, 0.f, 0.f, 0.f};

  short8 areg, breg;
  auto do_load = [&](int t) {
    int kk = t * 32 + scg;
    areg = *(const short8*)(Ab + (size_t)(m0 + srow) * K + kk);
    breg = *(const short8*)(W + (size_t)(n0 + srow) * K + kk);
  };
  auto do_write = [&](int buf) {
    *(short8*)&As[buf][srow][scg] = areg;
    *(short8*)&Bs[buf][srow][scg] = breg;
  };

  const int NT = K / 32;
  do_load(0);
  do_write(0);
  __syncthreads();
  for (int t = 0; t < NT; ++t) {
    const int cur = t & 1;
    if (t + 1 < NT) do_load(t + 1);
    short8 af0 = *(const short8*)&As[cur][wm * 32 + l15][l4 * 8];
    short8 af1 = *(const short8*)&As[cur][wm * 32 + 16 + l15][l4 * 8];
    short8 bf0 = *(const short8*)&Bs[cur][wn * 32 + l15][l4 * 8];
    short8 bf1 = *(const short8*)&Bs[cur][wn * 32 + 16 + l15][l4 * 8];
    acc[0][0] = __builtin_amdgcn_mfma_f32_16x16x32_bf16(af0, bf0, acc[0][0], 0, 0, 0);
    acc[0][1] = __builtin_amdgcn_mfma_f32_16x16x32_bf16(af0, bf1, acc[0][1], 0, 0, 0);
    acc[1][0] = __builtin_amdgcn_mfma_f32_16x16x32_bf16(af1, bf0, acc[1][0], 0, 0, 0);
    acc[1][1] = __builtin_amdgcn_mfma_f32_16x16x32_bf16(af1, bf1, acc[1][1], 0, 0, 0);
    if (t + 1 < NT) do_write(cur ^ 1);
    __syncthreads();
  }
#pragma unroll
  for (int nf = 0; nf < 2; ++nf) {
    int col = n0 + wn * 32 + nf * 16 + l15;
    float bv = bias[col];
#pragma unroll
    for (int mf = 0; mf < 2; ++mf) {
#pragma unroll
      for (int r = 0; r < 4; ++r) {
        int row = m0 + wm * 32 + mf * 16 + l4 * 4 + r;
        if (row < M) {
          float v = acc[mf][nf][r] + bv;
          if (ACT == 1) v = 0.5f * v * (1.f + erff(v * 0.70710678118654752440f));
          C[(size_t)row * N + col] = f2b(v);
        }
      }
    }
  }
}

// ---------------------------------------------------------------------------
// Fused GEMM + residual + LayerNorm, BM=16 x full row (N=256), grid 250.
// ---------------------------------------------------------------------------
template <int K>
__global__ __launch_bounds__(256) void gemm_ln16(
    const u16* __restrict__ A, const u16* __restrict__ W,
    const float* __restrict__ bias, const float* __restrict__ g,
    const float* __restrict__ be, float* __restrict__ X, u16* __restrict__ Xb)
{
  __shared__ __align__(16) u16 As[2][16][40];
  __shared__ __align__(16) u16 Bs[2][256][40];
  __shared__ float wsum[4][16], wsq[4][16];
  const int m0 = blockIdx.x * 16;
  const int tid = threadIdx.x;
  const int lane = tid & 63, wave = tid >> 6;
  const int l15 = lane & 15, l4 = lane >> 4;
  const int srow = tid >> 2, scg = (tid & 3) * 8;

  f32x4 acc[4];
#pragma unroll
  for (int i = 0; i < 4; ++i) acc[i] = (f32x4){0.f, 0.f, 0.f, 0.f};

  short8 areg, breg[4];
  auto do_load = [&](int t) {
    int kk = t * 32;
    if (tid < 64) {
      int arow = tid >> 2, acg = (tid & 3) * 8;
      areg = *(const short8*)(A + (size_t)(m0 + arow) * K + kk + acg);
    }
#pragma unroll
    for (int q = 0; q < 4; ++q)
      breg[q] = *(const short8*)(W + (size_t)(q * 64 + srow) * K + kk + scg);
  };
  auto do_write = [&](int buf) {
    if (tid < 64) {
      int arow = tid >> 2, acg = (tid & 3) * 8;
      *(short8*)&As[buf][arow][acg] = areg;
    }
#pragma unroll
    for (int q = 0; q < 4; ++q) *(short8*)&Bs[buf][q * 64 + srow][scg] = breg[q];
  };

  const int NT = K / 32;
  do_load(0);
  do_write(0);
  __syncthreads();
  for (int t = 0; t < NT; ++t) {
    const int cur = t & 1;
    if (t + 1 < NT) do_load(t + 1);
    short8 af = *(const short8*)&As[cur][l15][l4 * 8];
#pragma unroll
    for (int nf = 0; nf < 4; ++nf) {
      short8 bf = *(const short8*)&Bs[cur][wave * 64 + nf * 16 + l15][l4 * 8];
      acc[nf] = __builtin_amdgcn_mfma_f32_16x16x32_bf16(af, bf, acc[nf], 0, 0, 0);
    }
    if (t + 1 < NT) do_write(cur ^ 1);
    __syncthreads();
  }

#pragma unroll
  for (int nf = 0; nf < 4; ++nf) {
    int col = wave * 64 + nf * 16 + l15;
    float bv = bias[col];
#pragma unroll
    for (int r = 0; r < 4; ++r) {
      int row = m0 + l4 * 4 + r;
      acc[nf][r] += bv + X[(size_t)row * EE + col];
    }
  }
#pragma unroll
  for (int r = 0; r < 4; ++r) {
    float s = acc[0][r] + acc[1][r] + acc[2][r] + acc[3][r];
    float q = acc[0][r] * acc[0][r] + acc[1][r] * acc[1][r] +
              acc[2][r] * acc[2][r] + acc[3][r] * acc[3][r];
#pragma unroll
    for (int m = 1; m < 16; m <<= 1) {
      s += __shfl_xor(s, m, 64);
      q += __shfl_xor(q, m, 64);
    }
    if (l15 == 0) {
      wsum[wave][l4 * 4 + r] = s;
      wsq[wave][l4 * 4 + r] = q;
    }
  }
  __syncthreads();
#pragma unroll
  for (int r = 0; r < 4; ++r) {
    int rl = l4 * 4 + r;
    float Ssum = wsum[0][rl] + wsum[1][rl] + wsum[2][rl] + wsum[3][rl];
    float Qsum = wsq[0][rl] + wsq[1][rl] + wsq[2][rl] + wsq[3][rl];
    float mean = Ssum * (1.f / EE);
    float var = Qsum * (1.f / EE) - mean * mean;
    float inv = rsqrtf(var + 1e-5f);
    int row = m0 + rl;
#pragma unroll
    for (int nf = 0; nf < 4; ++nf) {
      int col = wave * 64 + nf * 16 + l15;
      float o = (acc[nf][r] - mean) * inv * g[col] + be[col];
      X[(size_t)row * EE + col] = o;
      Xb[(size_t)row * EE + col] = f2b(o);
    }
  }
}

// ---------------------------------------------------------------------------
// bf16 MFMA flash attention: 2 q-tiles per block (K/V staged ONCE per kv-tile,
// reused by both). grid (8, HH, BB) = 256 blocks.
// ---------------------------------------------------------------------------
__global__ __launch_bounds__(256) void attn_mfma(
    const u16* __restrict__ Qm, const u16* __restrict__ Km, const u16* __restrict__ Vm,
    const float* __restrict__ ts, u16* __restrict__ Om, int l)
{
  const int qt = blockIdx.x, h = blockIdx.y, b = blockIdx.z;
  const int tid = threadIdx.x;
  const int lane = tid & 63, wave = tid >> 6;
  const int l15 = lane & 15, l4 = lane >> 4;
  const float scale = ts[l * BB + b] * 0.17677669529663688110f;  // ts / sqrt(32)
  __shared__ __align__(16) u16 Ks[64][40];
  __shared__ __align__(16) u16 Vt[32][72];
  __shared__ __align__(16) u16 Pw[4][16][72];
  const int srow = tid >> 2, scg = (tid & 3) * 8;

  // per-q-tile state (statically indexed)
  short8 qf[2];
  float mrun[2][4], lrun[2][4];
  f32x4 Oacc[2][2];
#pragma unroll
  for (int u = 0; u < 2; ++u) {
    int q0 = (qt * 2 + u) * 64 + wave * 16;
    int qrow = q0 + l15;
    qf[u] = (short8){0, 0, 0, 0, 0, 0, 0, 0};
    if (qrow < SS)
      qf[u] = *(const short8*)(Qm + ((size_t)(b * SS + qrow)) * EE + h * DHH + l4 * 8);
#pragma unroll
    for (int r = 0; r < 4; ++r) { mrun[u][r] = -INFINITY; lrun[u][r] = 0.f; }
    Oacc[u][0] = (f32x4){0.f, 0.f, 0.f, 0.f};
    Oacc[u][1] = (f32x4){0.f, 0.f, 0.f, 0.f};
  }

  for (int k0 = 0; k0 < SS; k0 += 64) {
    int kn = SS - k0; if (kn > 64) kn = 64;
    __syncthreads();
    {
      short8 kv8 = {0, 0, 0, 0, 0, 0, 0, 0};
      if (srow < kn)
        kv8 = *(const short8*)(Km + ((size_t)(b * SS + k0 + srow)) * EE + h * DHH + scg);
      *(short8*)&Ks[srow][scg] = kv8;
    }
    {
      int d = tid & 31, kb = tid >> 5;
      u16 uu[8];
#pragma unroll
      for (int i = 0; i < 8; ++i) {
        int kv = kb * 8 + i;
        uu[i] = (kv < kn) ? Vm[((size_t)(b * SS + k0 + kv)) * EE + h * DHH + d] : (u16)0;
      }
      *(ushort4*)(&Vt[d][kb * 8])     = make_ushort4(uu[0], uu[1], uu[2], uu[3]);
      *(ushort4*)(&Vt[d][kb * 8 + 4]) = make_ushort4(uu[4], uu[5], uu[6], uu[7]);
    }
    __syncthreads();

#pragma unroll
    for (int u = 0; u < 2; ++u) {
      f32x4 sa[4];
#pragma unroll
      for (int nf = 0; nf < 4; ++nf) {
        short8 kf = *(const short8*)(&Ks[nf * 16 + l15][l4 * 8]);
        f32x4 zz = (f32x4){0.f, 0.f, 0.f, 0.f};
        sa[nf] = __builtin_amdgcn_mfma_f32_16x16x32_bf16(qf[u], kf, zz, 0, 0, 0);
      }
#pragma unroll
      for (int nf = 0; nf < 4; ++nf) {
        bool valid = (nf * 16 + l15) < kn;
#pragma unroll
        for (int r = 0; r < 4; ++r)
          sa[nf][r] = valid ? sa[nf][r] * scale : -INFINITY;
      }
      float pv[4][4];
#pragma unroll
      for (int r = 0; r < 4; ++r) {
        float tmax = fmaxf(fmaxf(sa[0][r], sa[1][r]), fmaxf(sa[2][r], sa[3][r]));
#pragma unroll
        for (int m = 1; m < 16; m <<= 1) tmax = fmaxf(tmax, __shfl_xor(tmax, m, 64));
        float mnew = fmaxf(mrun[u][r], tmax);
        float fac = expf(mrun[u][r] - mnew);
        float rsum = 0.f;
#pragma unroll
        for (int nf = 0; nf < 4; ++nf) {
          float p = expf(sa[nf][r] - mnew);
          pv[nf][r] = p;
          rsum += p;
        }
#pragma unroll
        for (int m = 1; m < 16; m <<= 1) rsum += __shfl_xor(rsum, m, 64);
        lrun[u][r] = lrun[u][r] * fac + rsum;
        mrun[u][r] = mnew;
        Oacc[u][0][r] *= fac;
        Oacc[u][1][r] *= fac;
      }
#pragma unroll
      for (int nf = 0; nf < 4; ++nf)
#pragma unroll
        for (int r = 0; r < 4; ++r)
          Pw[wave][l4 * 4 + r][nf * 16 + l15] = f2b(pv[nf][r]);
      asm volatile("s_waitcnt lgkmcnt(0)" ::: "memory");
      __builtin_amdgcn_sched_barrier(0);
#pragma unroll
      for (int ka = 0; ka < 2; ++ka) {
        short8 pa = *(const short8*)(&Pw[wave][l15][ka * 32 + l4 * 8]);
#pragma unroll
        for (int df = 0; df < 2; ++df) {
          short8 vf = *(const short8*)(&Vt[df * 16 + l15][ka * 32 + l4 * 8]);
          Oacc[u][df] = __builtin_amdgcn_mfma_f32_16x16x32_bf16(pa, vf, Oacc[u][df], 0, 0, 0);
        }
      }
      // Pw reuse across u is safe: per-wave DS ops are in-order, reads above
      // complete before the next u's writes issue.
      asm volatile("s_waitcnt lgkmcnt(0)" ::: "memory");
      __builtin_amdgcn_sched_barrier(0);
    }
  }
#pragma unroll
  for (int u = 0; u < 2; ++u) {
    int q0 = (qt * 2 + u) * 64 + wave * 16;
#pragma unroll
    for (int df = 0; df < 2; ++df)
#pragma unroll
      for (int r = 0; r < 4; ++r) {
        int qrow = q0 + l4 * 4 + r;
        if (qrow < SS)
          Om[((size_t)(b * SS + qrow)) * EE + h * DHH + df * 16 + l15] =
              f2b(Oacc[u][df][r] / lrun[u][r]);
      }
  }
}

// ---------------------------------------------------------------------------
// Attention-weighted pooling + LN + classifier; one batch per block.
// ---------------------------------------------------------------------------
__global__ __launch_bounds__(256) void final_kernel(
    const float* __restrict__ X, const float* __restrict__ g, const float* __restrict__ be,
    const float* __restrict__ w1, const float* __restrict__ b1,
    const float* __restrict__ w2, const float* __restrict__ b2,
    float* __restrict__ out)
{
  const int b = blockIdx.x, tid = threadIdx.x;
  const int lane = tid & 63, wid = tid >> 6;
  __shared__ float rs[SS];
  __shared__ float red[256];
  __shared__ float pooled[EE];
  __shared__ float h[128];
  for (int s = wid; s < SS; s += 4) {
    const float* xr = X + ((size_t)(b * SS + s)) * EE;
    float4 v = *(const float4*)(xr + lane * 4);
    float a = v.x + v.y + v.z + v.w;
    a = wredf_sum(a);
    if (lane == 0) rs[s] = a;
  }
  __syncthreads();
  float mx = -INFINITY;
  for (int s = tid; s < SS; s += 256) mx = fmaxf(mx, rs[s]);
  red[tid] = mx; __syncthreads();
  for (int w = 128; w > 0; w >>= 1) { if (tid < w) red[tid] = fmaxf(red[tid], red[tid + w]); __syncthreads(); }
  mx = red[0]; __syncthreads();
  float sme = 0.f;
  for (int s = tid; s < SS; s += 256) { float e2 = expf(rs[s] - mx); rs[s] = e2; sme += e2; }
  red[tid] = sme; __syncthreads();
  for (int w = 128; w > 0; w >>= 1) { if (tid < w) red[tid] += red[tid + w]; __syncthreads(); }
  float tot = red[0]; __syncthreads();
  float acc = 0.f;
  for (int s = 0; s < SS; ++s) acc += X[((size_t)(b * SS + s)) * EE + tid] * rs[s];
  acc /= tot;
  red[tid] = acc; __syncthreads();
  for (int w = 128; w > 0; w >>= 1) { if (tid < w) red[tid] += red[tid + w]; __syncthreads(); }
  float mean = red[0] * (1.f / EE); __syncthreads();
  float d = acc - mean;
  red[tid] = d * d; __syncthreads();
  for (int w = 128; w > 0; w >>= 1) { if (tid < w) red[tid] += red[tid + w]; __syncthreads(); }
  float var = red[0] * (1.f / EE);
  pooled[tid] = d * rsqrtf(var + 1e-5f) * g[tid] + be[tid];
  __syncthreads();
  if (tid < 128) {
    const float* w = w1 + (size_t)tid * EE;
    float a = b1[tid];
    for (int e = 0; e < EE; ++e) a += w[e] * pooled[e];
    h[tid] = fmaxf(a, 0.f);
  }
  __syncthreads();
  if (tid < 2) {
    const float* w = w2 + (size_t)tid * 128;
    float a = b2[tid];
    for (int j = 0; j < 128; ++j) a += w[j] * h[j];
    out[b * 2 + tid] = a;
  }
}

// ---------------------------------------------------------------------------
extern "C" void kernel_launch(void* const* d_in, const int* in_sizes, int n_in,
                              void* d_out, int out_size, void* d_ws, size_t ws_size,
                              hipStream_t stream) {
  (void)in_sizes; (void)n_in; (void)out_size; (void)ws_size;
  const float* seq    = (const float*)d_in[0];
  const float* ph_fw  = (const float*)d_in[1];
  const float* ph_db  = (const float*)d_in[2];
  const float* ph_law = (const float*)d_in[3];
  const float* ph_lab = (const float*)d_in[4];
  const float* emb_w1 = (const float*)d_in[5];
  const float* emb_b1 = (const float*)d_in[6];
  const float* emb_w2 = (const float*)d_in[7];
  const float* emb_b2 = (const float*)d_in[8];
  const float* eln_g  = (const float*)d_in[9];
  const float* eln_b  = (const float*)d_in[10];
  const float* pos    = (const float*)d_in[11];
  const float* qw     = (const float*)d_in[12];
  const float* qb     = (const float*)d_in[13];
  const float* kw     = (const float*)d_in[14];
  const float* kb     = (const float*)d_in[15];
  const float* vw     = (const float*)d_in[16];
  const float* vb     = (const float*)d_in[17];
  const float* pw1    = (const float*)d_in[18];
  const float* pb1    = (const float*)d_in[19];
  const float* pw2    = (const float*)d_in[20];
  const float* pb2    = (const float*)d_in[21];
  const float* ow     = (const float*)d_in[22];
  const float* obv    = (const float*)d_in[23];
  const float* lng    = (const float*)d_in[24];
  const float* lnb    = (const float*)d_in[25];
  const float* fw1    = (const float*)d_in[26];
  const float* fb1    = (const float*)d_in[27];
  const float* fw2    = (const float*)d_in[28];
  const float* fb2    = (const float*)d_in[29];
  const float* clng   = (const float*)d_in[30];
  const float* clnb   = (const float*)d_in[31];
  const float* cw1    = (const float*)d_in[32];
  const float* cb1    = (const float*)d_in[33];
  const float* cw2    = (const float*)d_in[34];
  const float* cb2    = (const float*)d_in[35];

  float* ws  = (float*)d_ws;
  float* pf  = ws;            // 24 floats
  float* tsv = ws + 32;       // 24 floats
  const size_t SL = (size_t)4096 * 256;
  float* X = ws + 256;                    // f32 residual stream
  u16* Xb   = (u16*)(X + SL);             // bf16 mirror of X
  u16* Qb   = Xb + SL;
  u16* Kb   = Qb + SL;
  u16* Vb   = Kb + SL;
  u16* ATTb = Vb + SL;
  u16* HIDb = ATTb + SL;                  // 4*SL ushorts (4096 x 1024)
  u16* Wb   = HIDb + 4 * SL;              // pre-converted bf16 weights
  u16* Wq  = Wb;
  u16* Wk  = Wb + WSEG;
  u16* Wv  = Wb + 2 * WSEG;
  u16* Wo  = Wb + 3 * WSEG;
  u16* Wf1 = Wb + 4 * WSEG;
  u16* Wf2 = Wb + 4 * WSEG + WFF;
  const int M = BB * SS;      // 4000

  phembed_kernel<<<BB + M / 4 + NCONV, 256, 0, stream>>>(
      seq, ph_fw, ph_db, ph_law, ph_lab, pf,
      emb_w1, emb_b1, emb_w2, emb_b2, eln_g, eln_b, pos, X, Xb,
      qw, kw, vw, ow, fw1, fw2, Wb);
  temp_kernel<<<LL * BB, 256, 0, stream>>>(pf, pw1, pb1, pw2, pb2, tsv);

  const int GM = 63;   // ceil(4000/64) for gemm_bt
  const int GL = 250;  // 4000/16 for gemm_ln16
  for (int l = 0; l < LL; ++l) {
    const size_t wo = (size_t)l * EE * EE;
    gemm_bt<0><<<dim3(GM, EE / 64, 3), 256, 0, stream>>>(
        Xb, Wq + wo, Wk + wo, Wv + wo, qb + l * EE, kb + l * EE, vb + l * EE,
        Qb, Kb, Vb, M, EE, EE);
    attn_mfma<<<dim3(8, HH, BB), 256, 0, stream>>>(Qb, Kb, Vb, tsv, ATTb, l);
    gemm_ln16<EE><<<GL, 256, 0, stream>>>(
        ATTb, Wo + wo, obv + l * EE, lng + l * EE, lnb + l * EE, X, Xb);
    gemm_bt<1><<<dim3(GM, FFD / 64, 1), 256, 0, stream>>>(
        Xb, Wf1 + (size_t)l * FFD * EE, Wf1 + (size_t)l * FFD * EE, Wf1 + (size_t)l * FFD * EE,
        fb1 + (size_t)l * FFD, fb1 + (size_t)l * FFD, fb1 + (size_t)l * FFD,
        HIDb, HIDb, HIDb, M, FFD, EE);
    gemm_ln16<FFD><<<GL, 256, 0, stream>>>(
        HIDb, Wf2 + (size_t)l * EE * FFD, fb2 + l * EE, lng + l * EE, lnb + l * EE, X, Xb);
  }

  final_kernel<<<BB, 256, 0, stream>>>(X, clng, clnb, cw1, cb1, cw2, cb2, (float*)d_out);
}

// Round 16
// 968.103 us; speedup vs baseline: 1.1391x; 1.1391x over previous
//
#include <hip/hip_runtime.h>
#include <math.h>

constexpr int BB = 4;       // batch
constexpr int SS = 1000;    // seq len
constexpr int INDIM = 5;
constexpr int EE = 256;     // embed
constexpr int LL = 6;       // layers
constexpr int HH = 8;       // heads
constexpr int DHH = 32;     // head dim
constexpr int NLM = 50;     // landmarks
constexpr int FFD = 1024;   // ff hidden
constexpr int NCONV = 576;  // weight-conversion blocks fused into phembed

constexpr long long WSEG = (long long)LL * EE * EE;        // qw/kw/vw/ow each
constexpr long long WFF  = (long long)LL * FFD * EE;       // fw1/fw2 each
constexpr long long WTOT = 4 * WSEG + 2 * WFF;

typedef short short8 __attribute__((ext_vector_type(8)));
typedef float f32x4 __attribute__((ext_vector_type(4)));
typedef unsigned short u16;
typedef unsigned long long u64;

__device__ inline u16 f2b(float f) {
  union { float f; unsigned u; } v; v.f = f;
  unsigned u = v.u;
  unsigned r = u + 0x7FFFu + ((u >> 16) & 1u);  // round-to-nearest-even
  return (u16)(r >> 16);
}
__device__ inline float b2f(u16 b) {
  union { unsigned u; float f; } v; v.u = ((unsigned)b) << 16;
  return v.f;
}
__device__ inline short8 pack8(float4 a, float4 b) {
  short8 r;
  r[0] = (short)f2b(a.x); r[1] = (short)f2b(a.y);
  r[2] = (short)f2b(a.z); r[3] = (short)f2b(a.w);
  r[4] = (short)f2b(b.x); r[5] = (short)f2b(b.y);
  r[6] = (short)f2b(b.z); r[7] = (short)f2b(b.w);
  return r;
}

__device__ inline double wred_sum(double v) {
#pragma unroll
  for (int m = 1; m < 64; m <<= 1) v += __shfl_xor(v, m, 64);
  return v;
}
__device__ inline double wred_min(double v) {
#pragma unroll
  for (int m = 1; m < 64; m <<= 1) v = fmin(v, __shfl_xor(v, m, 64));
  return v;
}
__device__ inline double wred_max(double v) {
#pragma unroll
  for (int m = 1; m < 64; m <<= 1) v = fmax(v, __shfl_xor(v, m, 64));
  return v;
}
__device__ inline float wredf_sum(float v) {
#pragma unroll
  for (int m = 1; m < 64; m <<= 1) v += __shfl_xor(v, m, 64);
  return v;
}
__device__ inline int sgnbit(double x) {
  return (int)((unsigned long long)__double_as_longlong(x) >> 63);
}

// ---------------------------------------------------------------------------
// Fused 256-thread kernel:
//   blocks [0,4)            : ph (4-wave LDS Householder, trailing-range split)
//   blocks [4,1004)         : embed (4 rows/block, one per wave)
//   blocks [1004,1004+NCONV): weight f32->bf16 conversion (overlaps ph)
// ---------------------------------------------------------------------------
struct PhS {
  double matA[NLM][51];
  union {
    u64 keys[1024];
    double vstore[NLM - 2][64];
  } u;
  double vbuf[64], wbuf[64];
  double pm[4][64];
  double dar[NLM], ear[NLM], e2a[NLM], tauA[NLM], evs[NLM];
  double gdl[NLM], gdd[NLM], gdu[NLM], gdu2[NLM], gz[NLM];
  float sm[SS];
  float lx[NLM], ly[NLM];
};
union FusedS { PhS ph; float h[4][128]; };

__global__ __launch_bounds__(256) void phembed_kernel(
    const float* __restrict__ seq, const float* __restrict__ ph_fw,
    const float* __restrict__ ph_db, const float* __restrict__ ph_law,
    const float* __restrict__ ph_lab, float* __restrict__ pf,
    const float* __restrict__ ew1, const float* __restrict__ eb1,
    const float* __restrict__ ew2, const float* __restrict__ eb2,
    const float* __restrict__ eg, const float* __restrict__ ebe,
    const float* __restrict__ pos, float* __restrict__ X, u16* __restrict__ Xb,
    const float* __restrict__ qw, const float* __restrict__ kw,
    const float* __restrict__ vw, const float* __restrict__ ow,
    const float* __restrict__ fw1, const float* __restrict__ fw2,
    u16* __restrict__ Wb)
{
  __shared__ FusedS S;
  const int tid = threadIdx.x;
  const int lane = tid & 63, wid = tid >> 6;

  if (blockIdx.x >= BB + SS) {
    // ===================== weight conversion path =====================
    const int cb = blockIdx.x - (BB + SS);
#pragma unroll
    for (int it = 0; it < 4; ++it) {
      long long v = ((long long)cb * 4 + it) * 256 + tid;
      long long e = v * 8;
      if (e >= WTOT) break;
      const float* src; long long off;
      if (e < WSEG)          { src = qw;  off = e; }
      else if (e < 2 * WSEG) { src = kw;  off = e - WSEG; }
      else if (e < 3 * WSEG) { src = vw;  off = e - 2 * WSEG; }
      else if (e < 4 * WSEG) { src = ow;  off = e - 3 * WSEG; }
      else if (e < 4 * WSEG + WFF) { src = fw1; off = e - 4 * WSEG; }
      else                   { src = fw2; off = e - 4 * WSEG - WFF; }
      float4 a = *(const float4*)(src + off);
      float4 b = *(const float4*)(src + off + 4);
      *(short8*)(Wb + e) = pack8(a, b);
    }
    return;
  }

  if (blockIdx.x < BB) {
    // ===================== ph path =====================
    const int b = blockIdx.x;
    PhS& P = S.ph;
    const float law0 = ph_law[0], law1 = ph_law[1], labv = ph_lab[0];
    for (int s = tid; s < 1024; s += 256) {
      u64 key;
      if (s < SS) {
        const float* p = seq + ((size_t)b * SS + s) * INDIM;
        float m = (p[0] + p[1] + p[2] + p[3] + p[4]) * 0.2f;
        P.sm[s] = m;
        float sc = (float)s * law0 + m * law1 + labv;
        unsigned u = __float_as_uint(sc);
        unsigned asc = (u & 0x80000000u) ? ~u : (u | 0x80000000u);
        key = ((u64)(~asc) << 32) | (unsigned)s;
      } else {
        key = (0xFFFFFFFFull << 32) | (unsigned)s;
      }
      P.u.keys[s] = key;
    }
    __syncthreads();
    for (int k = 2; k <= 1024; k <<= 1) {
      for (int j = k >> 1; j > 0; j >>= 1) {
        for (int i = tid; i < 1024; i += 256) {
          int ixj = i ^ j;
          if (ixj > i) {
            u64 a = P.u.keys[i], c = P.u.keys[ixj];
            bool up = ((i & k) == 0);
            if ((a > c) == up) { P.u.keys[i] = c; P.u.keys[ixj] = a; }
          }
        }
        __syncthreads();
      }
    }
    if (tid < NLM) {
      int id = (int)(P.u.keys[tid] & 0xFFFFFFFFull);
      P.lx[tid] = (float)id;
      P.ly[tid] = P.sm[id];
    }
    __syncthreads();   // keys dead; vstore aliases
    const float fwv = fabsf(ph_fw[0]);
    const float dbv = ph_db[0];
    for (int t = tid; t < NLM * NLM; t += 256) {
      int i = t / NLM, j = t % NLM;
      float dx = P.lx[i] - P.lx[j], dy = P.ly[i] - P.ly[j];
      float d2 = dx * dx + dy * dy;
      float dist = (d2 > 0.f) ? sqrtf(d2) : 0.f;
      float Kv = expf(-(dist * fwv + dbv));
      P.matA[i][j] = -(double)Kv;
    }
    __syncthreads();
    if (tid < NLM) {
      double rsum = 0.0;
      for (int j = 0; j < NLM; ++j) rsum -= P.matA[tid][j];
      P.matA[tid][tid] += rsum;  // exact cancellation -> lambda0 ~ 1e-15
    }
    __syncthreads();

    for (int k = 0; k <= NLM - 3; ++k) {
      const int m = NLM - 1 - k;
      if (wid == 0) {
        double x = (lane > k && lane < NLM) ? P.matA[lane][k] : 0.0;
        double x0 = __shfl(x, k + 1, 64);
        double sigma = wred_sum((lane > k + 1) ? x * x : 0.0);
        double beta, tau, scale;
        if (sigma == 0.0) { beta = x0; tau = 0.0; scale = 0.0; }
        else {
          double nrm = sqrt(x0 * x0 + sigma);
          beta = (x0 >= 0.0) ? -nrm : nrm;
          tau = (beta - x0) / beta;
          scale = 1.0 / (x0 - beta);
        }
        double v = (lane == k + 1) ? 1.0 : ((lane > k + 1 && lane < NLM) ? x * scale : 0.0);
        P.vbuf[lane] = v;
        P.u.vstore[k][lane] = v;
        if (lane == 0) { P.ear[k] = beta; P.tauA[k] = tau; }
      }
      __syncthreads();
      {
        int chunk = (m + 3) >> 2;
        int j0 = k + 1 + wid * chunk;
        int j1 = j0 + chunk; if (j1 > NLM) j1 = NLM;
        double partial = 0.0;
        if (lane < NLM)
          for (int j = j0; j < j1; ++j) partial += P.matA[lane][j] * P.vbuf[j];
        P.pm[wid][lane] = partial;
      }
      __syncthreads();
      if (wid == 0) {
        double tau = P.tauA[k];
        double p = 0.0;
        if (lane < NLM)
          p = (P.pm[0][lane] + P.pm[1][lane] + P.pm[2][lane] + P.pm[3][lane]) * tau;
        double vr = P.vbuf[lane];
        double dotvp = wred_sum(vr * p);
        double w = p - 0.5 * tau * dotvp * vr;
        P.wbuf[lane] = (lane < NLM) ? w : 0.0;
      }
      __syncthreads();
      {
        int chunk = (m + 4) >> 2;
        int j0 = k + wid * chunk;
        int j1 = j0 + chunk; if (j1 > NLM) j1 = NLM;
        if (lane < NLM) {
          double vr = P.vbuf[lane], wr = P.wbuf[lane];
          for (int j = j0; j < j1; ++j)
            P.matA[lane][j] -= vr * P.wbuf[j] + wr * P.vbuf[j];
        }
      }
      __syncthreads();
    }
    if (tid < NLM) P.dar[tid] = P.matA[tid][tid];
    if (tid == 0) P.ear[NLM - 2] = P.matA[NLM - 1][NLM - 2];
    __syncthreads();
    if (tid < NLM - 1) P.e2a[tid] = P.ear[tid] * P.ear[tid];
    __syncthreads();

    double lo_i = 1e300, hi_i = -1e300;
    if (lane < NLM) {
      double rl = (lane > 0) ? fabs(P.ear[lane - 1]) : 0.0;
      double rr = (lane < NLM - 1) ? fabs(P.ear[lane]) : 0.0;
      double dd = P.dar[lane];
      lo_i = dd - rl - rr;
      hi_i = dd + rl + rr;
    }
    double glo = wred_min(lo_i), ghi = wred_max(hi_i);

    if (tid < 100) {
      const int e = tid >> 1;
      const int side = tid & 1;
      const int need = e + 1;
      double lo = glo, hi = ghi;
      for (int it = 0; it < 24; ++it) {
        double third = (hi - lo) * (1.0 / 3.0);
        double x1 = lo + third, x2 = hi - third;
        double x = side ? x2 : x1;
        double p = P.dar[0] - x, q = 1.0;
        int c = sgnbit(p);
#pragma unroll 7
        for (int i = 1; i < NLM; ++i) {
          double n = (P.dar[i] - x) * p - P.e2a[i - 1] * q;
          if (n == 0.0) n = sgnbit(p) ? -1e-300 : 1e-300;
          c += (sgnbit(n) != sgnbit(p));
          long long an = __double_as_longlong(n) & 0x7fffffffffffffffLL;
          long long ap = __double_as_longlong(p) & 0x7fffffffffffffffLL;
          int E = (int)((an > ap ? an : ap) >> 52);
          int se = 2046 - E; se = se < 1 ? 1 : (se > 2045 ? 2045 : se);
          double s = __longlong_as_double((long long)se << 52);
          q = p * s; p = n * s;
        }
        int cp = __shfl_xor(c, 1, 64);
        int c1 = side ? cp : c;
        int c2 = side ? c : cp;
        if (c1 >= need) hi = x1;
        else if (c2 >= need) { lo = x1; hi = x2; }
        else lo = x2;
      }
      if (side == 0) P.evs[e] = 0.5 * (lo + hi);
    }
    __syncthreads();

    if (wid != 0) return;

    if (lane == 0) {
      double shift = P.evs[1];
      unsigned rs = 12345u;
      for (int i = 0; i < NLM; ++i) {
        rs = rs * 1103515245u + 12345u;
        P.gz[i] = ((double)((rs >> 8) & 0xFFFF)) / 65536.0 - 0.5;
      }
      for (int iter = 0; iter < 2; ++iter) {
        for (int i = 0; i < NLM; ++i) P.gdd[i] = P.dar[i] - shift;
        for (int i = 0; i < NLM - 1; ++i) { P.gdl[i] = P.ear[i]; P.gdu[i] = P.ear[i]; }
        for (int i = 0; i < NLM - 1; ++i) {
          if (fabs(P.gdd[i]) >= fabs(P.gdl[i])) {
            if (P.gdd[i] == 0.0) P.gdd[i] = 1e-280;
            double fact = P.gdl[i] / P.gdd[i];
            P.gdd[i + 1] -= fact * P.gdu[i];
            P.gz[i + 1] -= fact * P.gz[i];
            if (i < NLM - 2) P.gdu2[i] = 0.0;
          } else {
            double fact = P.gdd[i] / P.gdl[i];
            P.gdd[i] = P.gdl[i];
            double tmp = P.gdd[i + 1];
            P.gdd[i + 1] = P.gdu[i] - fact * tmp;
            if (i < NLM - 2) { P.gdu2[i] = P.gdu[i + 1]; P.gdu[i + 1] = -fact * P.gdu2[i]; }
            P.gdu[i] = tmp;
            double tz = P.gz[i]; P.gz[i] = P.gz[i + 1]; P.gz[i + 1] = tz - fact * P.gz[i];
          }
        }
        if (P.gdd[NLM - 1] == 0.0) P.gdd[NLM - 1] = 1e-280;
        P.gz[NLM - 1] /= P.gdd[NLM - 1];
        P.gz[NLM - 2] = (P.gz[NLM - 2] - P.gdu[NLM - 2] * P.gz[NLM - 1]) / P.gdd[NLM - 2];
        for (int i = NLM - 3; i >= 0; --i)
          P.gz[i] = (P.gz[i] - P.gdu[i] * P.gz[i + 1] - P.gdu2[i] * P.gz[i + 2]) / P.gdd[i];
        double nr = 0.0;
        for (int i = 0; i < NLM; ++i) nr += P.gz[i] * P.gz[i];
        nr = sqrt(nr);
        for (int i = 0; i < NLM; ++i) P.gz[i] /= nr;
      }
    }
    __builtin_amdgcn_wave_barrier();
    double fied = (lane < NLM) ? P.gz[lane] : 0.0;
    for (int k = NLM - 3; k >= 0; --k) {
      double v = P.u.vstore[k][lane];
      double dot = wred_sum(v * fied);
      fied -= P.tauA[k] * dot * v;
    }

    double myev = (lane < NLM) ? P.evs[lane] : 1e300;
    bool inR = (lane < NLM);
    double n0 = wred_sum((inR && myev < 1e-6) ? 1.0 : 0.0);
    double s0 = wred_sum((inR && myev < 1e-6) ? fabs(myev) : 0.0);
    double e0 = P.evs[0], e1 = P.evs[1];
    double e2 = P.evs[2], e3 = P.evs[3], e4 = P.evs[4], e5 = P.evs[5];
    double gap = e1 - e0;
    double m4 = (e2 + e3 + e4 + e5) * 0.25;
    double v4 = ((e2 - m4) * (e2 - m4) + (e3 - m4) * (e3 - m4) +
                 (e4 - m4) * (e4 - m4) + (e5 - m4) * (e5 - m4)) / 3.0;
    double fmean = wred_sum(inR ? fied : 0.0) / NLM;
    double fd = inR ? (fied - fmean) : 0.0;
    double fvar = wred_sum(fd * fd) / (NLM - 1);
    if (lane == 0) {
      float* o = pf + b * 6;
      o[0] = (float)n0;
      o[1] = (float)s0;
      o[2] = (float)gap;
      o[3] = (float)sqrt(fvar);
      o[4] = (float)m4;
      o[5] = (float)sqrt(v4);
    }
    return;
  }

  // ===================== embed path: 4 rows/block, one per wave =====================
  const int row = (blockIdx.x - BB) * 4 + wid;
  const int s = row % SS;
  float* hb = S.h[wid];
  float sv0, sv1, sv2, sv3, sv4;
  {
    const float* p = seq + (size_t)row * INDIM;
    sv0 = p[0]; sv1 = p[1]; sv2 = p[2]; sv3 = p[3]; sv4 = p[4];
  }
#pragma unroll
  for (int half = 0; half < 2; ++half) {
    int j = lane + half * 64;
    const float* w = ew1 + j * INDIM;
    float a = eb1[j] + w[0] * sv0 + w[1] * sv1 + w[2] * sv2 + w[3] * sv3 + w[4] * sv4;
    hb[j] = fmaxf(a, 0.f);
  }
  __builtin_amdgcn_wave_barrier();
  float o4[4];
#pragma unroll
  for (int q = 0; q < 4; ++q) {
    int e = lane * 4 + q;
    const float* w = ew2 + (size_t)e * 128;
    float a0 = 0.f, a1 = 0.f;
    for (int i = 0; i < 128; i += 8) {
      float4 wa = *(const float4*)(w + i);
      float4 wb = *(const float4*)(w + i + 4);
      a0 += wa.x * hb[i] + wa.y * hb[i + 1] + wa.z * hb[i + 2] + wa.w * hb[i + 3];
      a1 += wb.x * hb[i + 4] + wb.y * hb[i + 5] + wb.z * hb[i + 6] + wb.w * hb[i + 7];
    }
    o4[q] = eb2[e] + a0 + a1;
  }
  float ssum = o4[0] + o4[1] + o4[2] + o4[3];
  ssum = wredf_sum(ssum);
  float mean = ssum * (1.f / EE);
  float d0 = o4[0] - mean, d1 = o4[1] - mean, d2 = o4[2] - mean, d3 = o4[3] - mean;
  float qsum = d0 * d0 + d1 * d1 + d2 * d2 + d3 * d3;
  qsum = wredf_sum(qsum);
  float inv = rsqrtf(qsum * (1.f / EE) + 1e-5f);
  float4 gv = *(const float4*)(eg + lane * 4);
  float4 bv = *(const float4*)(ebe + lane * 4);
  float4 pv = *(const float4*)(pos + (size_t)s * EE + lane * 4);
  float4 outv = make_float4(d0 * inv * gv.x + bv.x + pv.x,
                            d1 * inv * gv.y + bv.y + pv.y,
                            d2 * inv * gv.z + bv.z + pv.z,
                            d3 * inv * gv.w + bv.w + pv.w);
  *(float4*)(X + (size_t)row * EE + lane * 4) = outv;
  *(ushort4*)(Xb + (size_t)row * EE + lane * 4) =
      make_ushort4(f2b(outv.x), f2b(outv.y), f2b(outv.z), f2b(outv.w));
}

// ---------------------------------------------------------------------------
// Per-(layer,batch) scalar attention temperature
// ---------------------------------------------------------------------------
__global__ __launch_bounds__(256) void temp_kernel(
    const float* __restrict__ pf, const float* __restrict__ w1, const float* __restrict__ b1,
    const float* __restrict__ w2, const float* __restrict__ b2, float* __restrict__ ts)
{
  const int l = blockIdx.x / BB, b = blockIdx.x % BB, tid = threadIdx.x;
  __shared__ float pfl[6];
  __shared__ float h[128];
  __shared__ float red[256];
  if (tid < 6) pfl[tid] = pf[b * 6 + tid];
  __syncthreads();
  if (tid < 128) {
    const float* w = w1 + ((size_t)l * 128 + tid) * 6;
    float a = b1[(size_t)l * 128 + tid];
#pragma unroll
    for (int i = 0; i < 6; ++i) a += w[i] * pfl[i];
    h[tid] = fmaxf(a, 0.f);
  }
  __syncthreads();
  const float* w = w2 + ((size_t)l * EE + tid) * 128;
  float a = b2[(size_t)l * EE + tid];
  for (int i = 0; i < 128; ++i) a += w[i] * h[i];
  float sg = 1.f / (1.f + expf(-a));
  red[tid] = sg; __syncthreads();
  for (int wd = 128; wd > 0; wd >>= 1) { if (tid < wd) red[tid] += red[tid + wd]; __syncthreads(); }
  if (tid == 0) ts[l * BB + b] = red[0] * (1.f / EE);
}

// ---------------------------------------------------------------------------
// bf16 MFMA GEMM: C(bf16) = A[MxK] @ W[NxK]^T + bias. W pre-converted bf16.
// Tile 64x64, dbuf LDS.
// ---------------------------------------------------------------------------
template <int ACT>
__global__ __launch_bounds__(256) void gemm_bt(
    const u16* __restrict__ Ab,
    const u16* __restrict__ W0, const u16* __restrict__ W1, const u16* __restrict__ W2,
    const float* __restrict__ bb0, const float* __restrict__ bb1, const float* __restrict__ bb2,
    u16* __restrict__ C0, u16* __restrict__ C1, u16* __restrict__ C2,
    int M, int N, int K)
{
  const int z = blockIdx.z;
  const u16* W = (z == 0) ? W0 : (z == 1) ? W1 : W2;
  const float* bias = (z == 0) ? bb0 : (z == 1) ? bb1 : bb2;
  u16* C = (z == 0) ? C0 : (z == 1) ? C1 : C2;
  __shared__ __align__(16) u16 As[2][64][40];
  __shared__ __align__(16) u16 Bs[2][64][40];
  const int m0 = blockIdx.x * 64, n0 = blockIdx.y * 64;
  const int tid = threadIdx.x;
  const int lane = tid & 63, wave = tid >> 6;
  const int wm = wave >> 1, wn = wave & 1;
  const int l15 = lane & 15, l4 = lane >> 4;
  const int srow = tid >> 2, scg = (tid & 3) * 8;

  f32x4 acc[2][2];
#pragma unroll
  for (int i = 0; i < 2; ++i)
#pragma unroll
    for (int j = 0; j < 2; ++j) acc[i][j] = (f32x4){0.f, 0.f, 0.f, 0.f};

  short8 areg, breg;
  auto do_load = [&](int t) {
    int kk = t * 32 + scg;
    areg = *(const short8*)(Ab + (size_t)(m0 + srow) * K + kk);
    breg = *(const short8*)(W + (size_t)(n0 + srow) * K + kk);
  };
  auto do_write = [&](int buf) {
    *(short8*)&As[buf][srow][scg] = areg;
    *(short8*)&Bs[buf][srow][scg] = breg;
  };

  const int NT = K / 32;
  do_load(0);
  do_write(0);
  __syncthreads();
  for (int t = 0; t < NT; ++t) {
    const int cur = t & 1;
    if (t + 1 < NT) do_load(t + 1);
    short8 af0 = *(const short8*)&As[cur][wm * 32 + l15][l4 * 8];
    short8 af1 = *(const short8*)&As[cur][wm * 32 + 16 + l15][l4 * 8];
    short8 bf0 = *(const short8*)&Bs[cur][wn * 32 + l15][l4 * 8];
    short8 bf1 = *(const short8*)&Bs[cur][wn * 32 + 16 + l15][l4 * 8];
    acc[0][0] = __builtin_amdgcn_mfma_f32_16x16x32_bf16(af0, bf0, acc[0][0], 0, 0, 0);
    acc[0][1] = __builtin_amdgcn_mfma_f32_16x16x32_bf16(af0, bf1, acc[0][1], 0, 0, 0);
    acc[1][0] = __builtin_amdgcn_mfma_f32_16x16x32_bf16(af1, bf0, acc[1][0], 0, 0, 0);
    acc[1][1] = __builtin_amdgcn_mfma_f32_16x16x32_bf16(af1, bf1, acc[1][1], 0, 0, 0);
    if (t + 1 < NT) do_write(cur ^ 1);
    __syncthreads();
  }
#pragma unroll
  for (int nf = 0; nf < 2; ++nf) {
    int col = n0 + wn * 32 + nf * 16 + l15;
    float bv = bias[col];
#pragma unroll
    for (int mf = 0; mf < 2; ++mf) {
#pragma unroll
      for (int r = 0; r < 4; ++r) {
        int row = m0 + wm * 32 + mf * 16 + l4 * 4 + r;
        if (row < M) {
          float v = acc[mf][nf][r] + bv;
          if (ACT == 1) v = 0.5f * v * (1.f + erff(v * 0.70710678118654752440f));
          C[(size_t)row * N + col] = f2b(v);
        }
      }
    }
  }
}

// ---------------------------------------------------------------------------
// Fused GEMM + residual + LayerNorm, BM=16 x full row (N=256), grid 250.
// ---------------------------------------------------------------------------
template <int K>
__global__ __launch_bounds__(256) void gemm_ln16(
    const u16* __restrict__ A, const u16* __restrict__ W,
    const float* __restrict__ bias, const float* __restrict__ g,
    const float* __restrict__ be, float* __restrict__ X, u16* __restrict__ Xb)
{
  __shared__ __align__(16) u16 As[2][16][40];
  __shared__ __align__(16) u16 Bs[2][256][40];
  __shared__ float wsum[4][16], wsq[4][16];
  const int m0 = blockIdx.x * 16;
  const int tid = threadIdx.x;
  const int lane = tid & 63, wave = tid >> 6;
  const int l15 = lane & 15, l4 = lane >> 4;
  const int srow = tid >> 2, scg = (tid & 3) * 8;

  f32x4 acc[4];
#pragma unroll
  for (int i = 0; i < 4; ++i) acc[i] = (f32x4){0.f, 0.f, 0.f, 0.f};

  short8 areg, breg[4];
  auto do_load = [&](int t) {
    int kk = t * 32;
    if (tid < 64) {
      int arow = tid >> 2, acg = (tid & 3) * 8;
      areg = *(const short8*)(A + (size_t)(m0 + arow) * K + kk + acg);
    }
#pragma unroll
    for (int q = 0; q < 4; ++q)
      breg[q] = *(const short8*)(W + (size_t)(q * 64 + srow) * K + kk + scg);
  };
  auto do_write = [&](int buf) {
    if (tid < 64) {
      int arow = tid >> 2, acg = (tid & 3) * 8;
      *(short8*)&As[buf][arow][acg] = areg;
    }
#pragma unroll
    for (int q = 0; q < 4; ++q) *(short8*)&Bs[buf][q * 64 + srow][scg] = breg[q];
  };

  const int NT = K / 32;
  do_load(0);
  do_write(0);
  __syncthreads();
  for (int t = 0; t < NT; ++t) {
    const int cur = t & 1;
    if (t + 1 < NT) do_load(t + 1);
    short8 af = *(const short8*)&As[cur][l15][l4 * 8];
#pragma unroll
    for (int nf = 0; nf < 4; ++nf) {
      short8 bf = *(const short8*)&Bs[cur][wave * 64 + nf * 16 + l15][l4 * 8];
      acc[nf] = __builtin_amdgcn_mfma_f32_16x16x32_bf16(af, bf, acc[nf], 0, 0, 0);
    }
    if (t + 1 < NT) do_write(cur ^ 1);
    __syncthreads();
  }

#pragma unroll
  for (int nf = 0; nf < 4; ++nf) {
    int col = wave * 64 + nf * 16 + l15;
    float bv = bias[col];
#pragma unroll
    for (int r = 0; r < 4; ++r) {
      int row = m0 + l4 * 4 + r;
      acc[nf][r] += bv + X[(size_t)row * EE + col];
    }
  }
#pragma unroll
  for (int r = 0; r < 4; ++r) {
    float s = acc[0][r] + acc[1][r] + acc[2][r] + acc[3][r];
    float q = acc[0][r] * acc[0][r] + acc[1][r] * acc[1][r] +
              acc[2][r] * acc[2][r] + acc[3][r] * acc[3][r];
#pragma unroll
    for (int m = 1; m < 16; m <<= 1) {
      s += __shfl_xor(s, m, 64);
      q += __shfl_xor(q, m, 64);
    }
    if (l15 == 0) {
      wsum[wave][l4 * 4 + r] = s;
      wsq[wave][l4 * 4 + r] = q;
    }
  }
  __syncthreads();
#pragma unroll
  for (int r = 0; r < 4; ++r) {
    int rl = l4 * 4 + r;
    float Ssum = wsum[0][rl] + wsum[1][rl] + wsum[2][rl] + wsum[3][rl];
    float Qsum = wsq[0][rl] + wsq[1][rl] + wsq[2][rl] + wsq[3][rl];
    float mean = Ssum * (1.f / EE);
    float var = Qsum * (1.f / EE) - mean * mean;
    float inv = rsqrtf(var + 1e-5f);
    int row = m0 + rl;
#pragma unroll
    for (int nf = 0; nf < 4; ++nf) {
      int col = wave * 64 + nf * 16 + l15;
      float o = (acc[nf][r] - mean) * inv * g[col] + be[col];
      X[(size_t)row * EE + col] = o;
      Xb[(size_t)row * EE + col] = f2b(o);
    }
  }
}

// ---------------------------------------------------------------------------
// bf16 MFMA flash attention (bf16 in/out), per-sample scalar temperature.
// grid (16, HH, BB) = 512 blocks; 1 q-tile per block (round-14 config).
// ---------------------------------------------------------------------------
__global__ __launch_bounds__(256) void attn_mfma(
    const u16* __restrict__ Qm, const u16* __restrict__ Km, const u16* __restrict__ Vm,
    const float* __restrict__ ts, u16* __restrict__ Om, int l)
{
  const int qt = blockIdx.x, h = blockIdx.y, b = blockIdx.z;
  const int tid = threadIdx.x;
  const int lane = tid & 63, wave = tid >> 6;
  const int l15 = lane & 15, l4 = lane >> 4;
  const float scale = ts[l * BB + b] * 0.17677669529663688110f;  // ts / sqrt(32)
  __shared__ __align__(16) u16 Ks[64][40];
  __shared__ __align__(16) u16 Vt[32][72];
  __shared__ __align__(16) u16 Pw[4][16][72];
  const int q0 = qt * 64 + wave * 16;
  const int srow = tid >> 2, scg = (tid & 3) * 8;

  short8 qf = {0, 0, 0, 0, 0, 0, 0, 0};
  {
    int qrow = q0 + l15;
    if (qrow < SS)
      qf = *(const short8*)(Qm + ((size_t)(b * SS + qrow)) * EE + h * DHH + l4 * 8);
  }

  float mrun[4] = {-INFINITY, -INFINITY, -INFINITY, -INFINITY};
  float lrun[4] = {0.f, 0.f, 0.f, 0.f};
  f32x4 Oacc[2];
  Oacc[0] = (f32x4){0.f, 0.f, 0.f, 0.f};
  Oacc[1] = (f32x4){0.f, 0.f, 0.f, 0.f};

  for (int k0 = 0; k0 < SS; k0 += 64) {
    int kn = SS - k0; if (kn > 64) kn = 64;
    __syncthreads();
    {
      short8 kv8 = {0, 0, 0, 0, 0, 0, 0, 0};
      if (srow < kn)
        kv8 = *(const short8*)(Km + ((size_t)(b * SS + k0 + srow)) * EE + h * DHH + scg);
      *(short8*)&Ks[srow][scg] = kv8;
    }
    {
      int d = tid & 31, kb = tid >> 5;
      u16 uu[8];
#pragma unroll
      for (int i = 0; i < 8; ++i) {
        int kv = kb * 8 + i;
        uu[i] = (kv < kn) ? Vm[((size_t)(b * SS + k0 + kv)) * EE + h * DHH + d] : (u16)0;
      }
      *(ushort4*)(&Vt[d][kb * 8])     = make_ushort4(uu[0], uu[1], uu[2], uu[3]);
      *(ushort4*)(&Vt[d][kb * 8 + 4]) = make_ushort4(uu[4], uu[5], uu[6], uu[7]);
    }
    __syncthreads();

    f32x4 sa[4];
#pragma unroll
    for (int nf = 0; nf < 4; ++nf) {
      short8 kf = *(const short8*)(&Ks[nf * 16 + l15][l4 * 8]);
      f32x4 zz = (f32x4){0.f, 0.f, 0.f, 0.f};
      sa[nf] = __builtin_amdgcn_mfma_f32_16x16x32_bf16(qf, kf, zz, 0, 0, 0);
    }
#pragma unroll
    for (int nf = 0; nf < 4; ++nf) {
      bool valid = (nf * 16 + l15) < kn;
#pragma unroll
      for (int r = 0; r < 4; ++r)
        sa[nf][r] = valid ? sa[nf][r] * scale : -INFINITY;
    }
    float pv[4][4];
#pragma unroll
    for (int r = 0; r < 4; ++r) {
      float tmax = fmaxf(fmaxf(sa[0][r], sa[1][r]), fmaxf(sa[2][r], sa[3][r]));
#pragma unroll
      for (int m = 1; m < 16; m <<= 1) tmax = fmaxf(tmax, __shfl_xor(tmax, m, 64));
      float mnew = fmaxf(mrun[r], tmax);
      float fac = expf(mrun[r] - mnew);
      float rsum = 0.f;
#pragma unroll
      for (int nf = 0; nf < 4; ++nf) {
        float p = expf(sa[nf][r] - mnew);
        pv[nf][r] = p;
        rsum += p;
      }
#pragma unroll
      for (int m = 1; m < 16; m <<= 1) rsum += __shfl_xor(rsum, m, 64);
      lrun[r] = lrun[r] * fac + rsum;
      mrun[r] = mnew;
      Oacc[0][r] *= fac;
      Oacc[1][r] *= fac;
    }
#pragma unroll
    for (int nf = 0; nf < 4; ++nf)
#pragma unroll
      for (int r = 0; r < 4; ++r)
        Pw[wave][l4 * 4 + r][nf * 16 + l15] = f2b(pv[nf][r]);
    asm volatile("s_waitcnt lgkmcnt(0)" ::: "memory");
    __builtin_amdgcn_sched_barrier(0);
#pragma unroll
    for (int ka = 0; ka < 2; ++ka) {
      short8 pa = *(const short8*)(&Pw[wave][l15][ka * 32 + l4 * 8]);
#pragma unroll
      for (int df = 0; df < 2; ++df) {
        short8 vf = *(const short8*)(&Vt[df * 16 + l15][ka * 32 + l4 * 8]);
        Oacc[df] = __builtin_amdgcn_mfma_f32_16x16x32_bf16(pa, vf, Oacc[df], 0, 0, 0);
      }
    }
  }
#pragma unroll
  for (int df = 0; df < 2; ++df)
#pragma unroll
    for (int r = 0; r < 4; ++r) {
      int qrow = q0 + l4 * 4 + r;
      if (qrow < SS)
        Om[((size_t)(b * SS + qrow)) * EE + h * DHH + df * 16 + l15] = f2b(Oacc[df][r] / lrun[r]);
    }
}

// ---------------------------------------------------------------------------
// Attention-weighted pooling + LN + classifier; one batch per block.
// ---------------------------------------------------------------------------
__global__ __launch_bounds__(256) void final_kernel(
    const float* __restrict__ X, const float* __restrict__ g, const float* __restrict__ be,
    const float* __restrict__ w1, const float* __restrict__ b1,
    const float* __restrict__ w2, const float* __restrict__ b2,
    float* __restrict__ out)
{
  const int b = blockIdx.x, tid = threadIdx.x;
  const int lane = tid & 63, wid = tid >> 6;
  __shared__ float rs[SS];
  __shared__ float red[256];
  __shared__ float pooled[EE];
  __shared__ float h[128];
  for (int s = wid; s < SS; s += 4) {
    const float* xr = X + ((size_t)(b * SS + s)) * EE;
    float4 v = *(const float4*)(xr + lane * 4);
    float a = v.x + v.y + v.z + v.w;
    a = wredf_sum(a);
    if (lane == 0) rs[s] = a;
  }
  __syncthreads();
  float mx = -INFINITY;
  for (int s = tid; s < SS; s += 256) mx = fmaxf(mx, rs[s]);
  red[tid] = mx; __syncthreads();
  for (int w = 128; w > 0; w >>= 1) { if (tid < w) red[tid] = fmaxf(red[tid], red[tid + w]); __syncthreads(); }
  mx = red[0]; __syncthreads();
  float sme = 0.f;
  for (int s = tid; s < SS; s += 256) { float e2 = expf(rs[s] - mx); rs[s] = e2; sme += e2; }
  red[tid] = sme; __syncthreads();
  for (int w = 128; w > 0; w >>= 1) { if (tid < w) red[tid] += red[tid + w]; __syncthreads(); }
  float tot = red[0]; __syncthreads();
  float acc = 0.f;
  for (int s = 0; s < SS; ++s) acc += X[((size_t)(b * SS + s)) * EE + tid] * rs[s];
  acc /= tot;
  red[tid] = acc; __syncthreads();
  for (int w = 128; w > 0; w >>= 1) { if (tid < w) red[tid] += red[tid + w]; __syncthreads(); }
  float mean = red[0] * (1.f / EE); __syncthreads();
  float d = acc - mean;
  red[tid] = d * d; __syncthreads();
  for (int w = 128; w > 0; w >>= 1) { if (tid < w) red[tid] += red[tid + w]; __syncthreads(); }
  float var = red[0] * (1.f / EE);
  pooled[tid] = d * rsqrtf(var + 1e-5f) * g[tid] + be[tid];
  __syncthreads();
  if (tid < 128) {
    const float* w = w1 + (size_t)tid * EE;
    float a = b1[tid];
    for (int e = 0; e < EE; ++e) a += w[e] * pooled[e];
    h[tid] = fmaxf(a, 0.f);
  }
  __syncthreads();
  if (tid < 2) {
    const float* w = w2 + (size_t)tid * 128;
    float a = b2[tid];
    for (int j = 0; j < 128; ++j) a += w[j] * h[j];
    out[b * 2 + tid] = a;
  }
}

// ---------------------------------------------------------------------------
extern "C" void kernel_launch(void* const* d_in, const int* in_sizes, int n_in,
                              void* d_out, int out_size, void* d_ws, size_t ws_size,
                              hipStream_t stream) {
  (void)in_sizes; (void)n_in; (void)out_size; (void)ws_size;
  const float* seq    = (const float*)d_in[0];
  const float* ph_fw  = (const float*)d_in[1];
  const float* ph_db  = (const float*)d_in[2];
  const float* ph_law = (const float*)d_in[3];
  const float* ph_lab = (const float*)d_in[4];
  const float* emb_w1 = (const float*)d_in[5];
  const float* emb_b1 = (const float*)d_in[6];
  const float* emb_w2 = (const float*)d_in[7];
  const float* emb_b2 = (const float*)d_in[8];
  const float* eln_g  = (const float*)d_in[9];
  const float* eln_b  = (const float*)d_in[10];
  const float* pos    = (const float*)d_in[11];
  const float* qw     = (const float*)d_in[12];
  const float* qb     = (const float*)d_in[13];
  const float* kw     = (const float*)d_in[14];
  const float* kb     = (const float*)d_in[15];
  const float* vw     = (const float*)d_in[16];
  const float* vb     = (const float*)d_in[17];
  const float* pw1    = (const float*)d_in[18];
  const float* pb1    = (const float*)d_in[19];
  const float* pw2    = (const float*)d_in[20];
  const float* pb2    = (const float*)d_in[21];
  const float* ow     = (const float*)d_in[22];
  const float* obv    = (const float*)d_in[23];
  const float* lng    = (const float*)d_in[24];
  const float* lnb    = (const float*)d_in[25];
  const float* fw1    = (const float*)d_in[26];
  const float* fb1    = (const float*)d_in[27];
  const float* fw2    = (const float*)d_in[28];
  const float* fb2    = (const float*)d_in[29];
  const float* clng   = (const float*)d_in[30];
  const float* clnb   = (const float*)d_in[31];
  const float* cw1    = (const float*)d_in[32];
  const float* cb1    = (const float*)d_in[33];
  const float* cw2    = (const float*)d_in[34];
  const float* cb2    = (const float*)d_in[35];

  float* ws  = (float*)d_ws;
  float* pf  = ws;            // 24 floats
  float* tsv = ws + 32;       // 24 floats
  const size_t SL = (size_t)4096 * 256;
  float* X = ws + 256;                    // f32 residual stream
  u16* Xb   = (u16*)(X + SL);             // bf16 mirror of X
  u16* Qb   = Xb + SL;
  u16* Kb   = Qb + SL;
  u16* Vb   = Kb + SL;
  u16* ATTb = Vb + SL;
  u16* HIDb = ATTb + SL;                  // 4*SL ushorts (4096 x 1024)
  u16* Wb   = HIDb + 4 * SL;              // pre-converted bf16 weights
  u16* Wq  = Wb;
  u16* Wk  = Wb + WSEG;
  u16* Wv  = Wb + 2 * WSEG;
  u16* Wo  = Wb + 3 * WSEG;
  u16* Wf1 = Wb + 4 * WSEG;
  u16* Wf2 = Wb + 4 * WSEG + WFF;
  const int M = BB * SS;      // 4000

  phembed_kernel<<<BB + M / 4 + NCONV, 256, 0, stream>>>(
      seq, ph_fw, ph_db, ph_law, ph_lab, pf,
      emb_w1, emb_b1, emb_w2, emb_b2, eln_g, eln_b, pos, X, Xb,
      qw, kw, vw, ow, fw1, fw2, Wb);
  temp_kernel<<<LL * BB, 256, 0, stream>>>(pf, pw1, pb1, pw2, pb2, tsv);

  const int GM = 63;   // ceil(4000/64) for gemm_bt
  const int GL = 250;  // 4000/16 for gemm_ln16
  for (int l = 0; l < LL; ++l) {
    const size_t wo = (size_t)l * EE * EE;
    gemm_bt<0><<<dim3(GM, EE / 64, 3), 256, 0, stream>>>(
        Xb, Wq + wo, Wk + wo, Wv + wo, qb + l * EE, kb + l * EE, vb + l * EE,
        Qb, Kb, Vb, M, EE, EE);
    attn_mfma<<<dim3(16, HH, BB), 256, 0, stream>>>(Qb, Kb, Vb, tsv, ATTb, l);
    gemm_ln16<EE><<<GL, 256, 0, stream>>>(
        ATTb, Wo + wo, obv + l * EE, lng + l * EE, lnb + l * EE, X, Xb);
    gemm_bt<1><<<dim3(GM, FFD / 64, 1), 256, 0, stream>>>(
        Xb, Wf1 + (size_t)l * FFD * EE, Wf1 + (size_t)l * FFD * EE, Wf1 + (size_t)l * FFD * EE,
        fb1 + (size_t)l * FFD, fb1 + (size_t)l * FFD, fb1 + (size_t)l * FFD,
        HIDb, HIDb, HIDb, M, FFD, EE);
    gemm_ln16<FFD><<<GL, 256, 0, stream>>>(
        HIDb, Wf2 + (size_t)l * EE * FFD, fb2 + l * EE, lng + l * EE, lnb + l * EE, X, Xb);
  }

  final_kernel<<<BB, 256, 0, stream>>>(X, clng, clnb, cw1, cb1, cw2, cb2, (float*)d_out);
}